// Round 3
// baseline (42599.829 us; speedup 1.0000x reference)
//
#include <hip/hip_runtime.h>
#include <cmath>

typedef __attribute__((ext_vector_type(4))) float f32x4;
typedef __attribute__((ext_vector_type(8))) short s16x8;
typedef __attribute__((ext_vector_type(4))) short s16x4;
typedef unsigned long long u64;

#define TSTEPS 4096
#define NCU 32

__device__ __forceinline__ short f2bf(float f) {
  unsigned u = __float_as_uint(f);
  unsigned r = (u + 0x7FFFu + ((u >> 16) & 1u)) >> 16;
  return (short)r;
}
__device__ __forceinline__ float bf2f(short s) {
  return __uint_as_float(((unsigned)(unsigned short)s) << 16);
}
__device__ __forceinline__ unsigned umin2(unsigned a, unsigned b) { return a < b ? a : b; }

// ---- pre1 layout: [t][cu][m][32j] : idx = t*8192 + cu*256 + m*32 + jl ----
__global__ void __launch_bounds__(256) pre_gemm(
    const float* __restrict__ x, const float* __restrict__ W1,
    const float* __restrict__ b1, float* __restrict__ pre1)
{
  __shared__ float As[16][136];
  __shared__ float Bs[16][136];
  const int tid = threadIdx.x;
  const int m0 = blockIdx.x * 128, j0 = blockIdx.y * 128;
  const int r = tid >> 1, half = tid & 1;
  const int tx = tid & 15, ty = tid >> 4;

  float acc[8][8];
#pragma unroll
  for (int a = 0; a < 8; a++)
#pragma unroll
    for (int b = 0; b < 8; b++) acc[a][b] = 0.f;

  const int row = m0 + r;  // row = t*8 + b
  const float* xrow = x + (((size_t)(row & 7) * 4096) + (size_t)(row >> 3)) * 512;
  const float* wrow = W1 + (size_t)(j0 + r) * 1024;  // W1a = cols [0,512)

  for (int k0 = 0; k0 < 512; k0 += 16) {
    f32x4 a0 = *(const f32x4*)(xrow + k0 + half * 8);
    f32x4 a1 = *(const f32x4*)(xrow + k0 + half * 8 + 4);
    f32x4 w0 = *(const f32x4*)(wrow + k0 + half * 8);
    f32x4 w1 = *(const f32x4*)(wrow + k0 + half * 8 + 4);
    __syncthreads();
#pragma unroll
    for (int q = 0; q < 4; q++) {
      As[half * 8 + q][r] = a0[q];
      As[half * 8 + 4 + q][r] = a1[q];
      Bs[half * 8 + q][r] = w0[q];
      Bs[half * 8 + 4 + q][r] = w1[q];
    }
    __syncthreads();
#pragma unroll
    for (int kk = 0; kk < 16; kk++) {
      f32x4 ra0 = *(const f32x4*)&As[kk][ty * 8];
      f32x4 ra1 = *(const f32x4*)&As[kk][ty * 8 + 4];
      f32x4 rb0 = *(const f32x4*)&Bs[kk][tx * 8];
      f32x4 rb1 = *(const f32x4*)&Bs[kk][tx * 8 + 4];
#pragma unroll
      for (int a = 0; a < 4; a++)
#pragma unroll
        for (int b = 0; b < 4; b++) {
          acc[a][b]         += ra0[a] * rb0[b];
          acc[a][b + 4]     += ra0[a] * rb1[b];
          acc[a + 4][b]     += ra1[a] * rb0[b];
          acc[a + 4][b + 4] += ra1[a] * rb1[b];
        }
    }
  }
  float bias[8];
#pragma unroll
  for (int b = 0; b < 8; b++) bias[b] = b1[j0 + tx * 8 + b];

  // epilogue to [t][cu][m][32] layout
  const int tt = (m0 >> 3) + ty;        // t index (a only varies m within it)
  const int col0 = j0 + tx * 8;
  const int c2 = col0 >> 5, jl0 = col0 & 31;
  float* dst = pre1 + (size_t)tt * 8192 + (size_t)c2 * 256 + jl0;
#pragma unroll
  for (int a = 0; a < 8; a++) {
    f32x4 v0, v1;
#pragma unroll
    for (int b = 0; b < 4; b++) { v0[b] = acc[a][b] + bias[b]; v1[b] = acc[a][b + 4] + bias[b + 4]; }
    *(f32x4*)(dst + a * 32) = v0;
    *(f32x4*)(dst + a * 32 + 4) = v1;
  }
}

// ---------------- persistent sequential scan: 32 blocks, j-sliced ----------------
__global__ void __launch_bounds__(256) seq_scan(
    const float* __restrict__ W1, const float* __restrict__ W2,
    const float* __restrict__ b2, const float* __restrict__ pre1,
    float* __restrict__ out, float* __restrict__ accbuf,
    unsigned* __restrict__ bar)
{
  const int c = blockIdx.x;          // 0..31, owns j in [32c, 32c+32)
  const int tid = threadIdx.x;
  const int l = tid & 63;
  const int w = tid >> 6;            // wave 0..3

  extern __shared__ char lds[];
  short* w1bh = (short*)lds;                 // [32][520]
  short* w1bl = w1bh + 32 * 520;
  short* w2h  = w1bl + 32 * 520;             // [512][36]
  short* w2l  = w2h + 512 * 36;
  short* memh = w2l + 512 * 36;              // [9][520]
  short* meml = memh + 9 * 520;
  short* hh   = meml + 9 * 520;              // [9][40]
  short* hl   = hh + 9 * 40;
  float* scr  = (float*)(hl + 9 * 40);       // 512 f32

  // ---- preload weight slices into LDS as bf16 hi/lo splits ----
  for (int e = tid; e < 32 * 128; e += 256) {
    int jl = e >> 7, k4 = (e & 127) << 2;
    f32x4 v = *(const f32x4*)(W1 + (size_t)(c * 32 + jl) * 1024 + 512 + k4);
#pragma unroll
    for (int q = 0; q < 4; q++) {
      short hi = f2bf(v[q]);
      w1bh[jl * 520 + k4 + q] = hi;
      w1bl[jl * 520 + k4 + q] = f2bf(v[q] - bf2f(hi));
    }
  }
  for (int e = tid; e < 512 * 8; e += 256) {
    int i = e >> 3, j4 = (e & 7) << 2;
    f32x4 v = *(const f32x4*)(W2 + (size_t)i * 1024 + c * 32 + j4);
#pragma unroll
    for (int q = 0; q < 4; q++) {
      short hi = f2bf(v[q]);
      w2h[i * 36 + j4 + q] = hi;
      w2l[i * 36 + j4 + q] = f2bf(v[q] - bf2f(hi));
    }
  }
  for (int e = tid; e < 9 * 520; e += 256) { memh[e] = 0; meml[e] = 0; }
  for (int e = tid; e < 9 * 40; e += 256)  { hh[e] = 0; hl[e] = 0; }

  // gate-phase ownership: (m = tid>>5, i = (tid&31)*16 + q)
  const int mg = tid >> 5;
  const int i0own = (tid & 31) * 16;
  float memr[16];
  float b2r[16];
#pragma unroll
  for (int q = 0; q < 16; q++) { memr[q] = 0.f; b2r[q] = b2[i0own + q]; }

  // phase-1 epilogue threads: waves 0,1 lanes 0..31 own (m = (l>>4)*4+rr, jg)
  const int jt = w & 1, kh = w >> 1;
  const int m_ep = (l >> 4) * 4;
  const bool ep = (w < 2) && (l < 32);
  const float* p1base = pre1 + (size_t)c * 256 + m_ep * 32 + jt * 16 + (l & 15);
  float p1r[4];
  if (ep) {
#pragma unroll
    for (int rr = 0; rr < 4; rr++) p1r[rr] = p1base[rr * 32];   // t=0
  }

  const int arow = ((l & 15) < 8) ? (l & 15) : 8;
  const int aoff = arow * 520 + (l >> 4) * 8;
  const int boff = (jt * 16 + (l & 15)) * 520 + (l >> 4) * 8;
  const int haoff = arow * 40 + (l >> 4) * 8;
  const int shard = c & 3;

  __syncthreads();

  for (int t = 0; t < TSTEPS; t++) {
    // ===== phase 1: h[:, our 32 j] = gelu(pre1 + mem @ W1b^T) =====
    {
      f32x4 a0 = {0.f,0.f,0.f,0.f}, a1 = a0, a2 = a0;
#pragma unroll
      for (int ks = 0; ks < 8; ks++) {
        const int ko = kh * 256 + ks * 32;
        s16x8 ah = *(const s16x8*)(memh + aoff + ko);
        s16x8 al = *(const s16x8*)(meml + aoff + ko);
        s16x8 bh = *(const s16x8*)(w1bh + boff + ko);
        s16x8 bl = *(const s16x8*)(w1bl + boff + ko);
        a0 = __builtin_amdgcn_mfma_f32_16x16x32_bf16(ah, bh, a0, 0, 0, 0);
        a1 = __builtin_amdgcn_mfma_f32_16x16x32_bf16(al, bh, a1, 0, 0, 0);
        a2 = __builtin_amdgcn_mfma_f32_16x16x32_bf16(ah, bl, a2, 0, 0, 0);
      }
      f32x4 acc = a0 + a1 + a2;
      if (w >= 2) *(f32x4*)(scr + (w - 2) * 256 + l * 4) = acc;
      __syncthreads();                                   // sync1: scr ready
      if (w < 2) {
        acc += *(const f32x4*)(scr + w * 256 + l * 4);
        if (l < 32) {
#pragma unroll
          for (int rr = 0; rr < 4; rr++) {
            float xv = acc[rr] + p1r[rr];
            float hv = 0.5f * xv * (1.0f + erff(xv * 0.70710678118654752f));
            short hhi = f2bf(hv);
            hh[(m_ep + rr) * 40 + jt * 16 + (l & 15)] = hhi;
            hl[(m_ep + rr) * 40 + jt * 16 + (l & 15)] = f2bf(hv - bf2f(hhi));
          }
        }
      }
    }
    __syncthreads();                                     // sync2: h ready

    // ===== phase 2: partial[m,i] += h_slice @ W2_slice^T, atomicAdd into shard =====
    {
      float* accw = accbuf + ((size_t)(t & 3) * 4 + shard) * 4096;
      s16x8 ha = *(const s16x8*)(hh + haoff);
      s16x8 hb = *(const s16x8*)(hl + haoff);
      const int n0 = w * 128;
#pragma unroll
      for (int tt = 0; tt < 8; tt++) {
        const int tl = (tt + c) & 7;
        const int icol = n0 + tl * 16 + (l & 15);
        const int woff = icol * 36 + (l >> 4) * 8;
        s16x8 bh, bl;
        *(s16x4*)&bh = *(const s16x4*)(w2h + woff);
        *((s16x4*)&bh + 1) = *(const s16x4*)(w2h + woff + 4);
        *(s16x4*)&bl = *(const s16x4*)(w2l + woff);
        *((s16x4*)&bl + 1) = *(const s16x4*)(w2l + woff + 4);
        f32x4 p0 = {0.f,0.f,0.f,0.f}, p1 = p0, p2 = p0;
        p0 = __builtin_amdgcn_mfma_f32_16x16x32_bf16(ha, bh, p0, 0, 0, 0);
        p1 = __builtin_amdgcn_mfma_f32_16x16x32_bf16(hb, bh, p1, 0, 0, 0);
        p2 = __builtin_amdgcn_mfma_f32_16x16x32_bf16(ha, bl, p2, 0, 0, 0);
        f32x4 p = p0 + p1 + p2;
        if (l < 32) {
          const int mrow = (l >> 4) * 4;
#pragma unroll
          for (int rr = 0; rr < 4; rr++)
            atomicAdd(accw + ((mrow + rr) << 9) + icol, p[rr]);
        }
      }
    }

    // ===== per-wave arrival: drain own VMEM, then bump this wave's counter =====
    __builtin_amdgcn_sched_barrier(0);
    __builtin_amdgcn_s_waitcnt(0);          // vmcnt(0) lgkmcnt(0) expcnt(0)
    __builtin_amdgcn_sched_barrier(0);
    if (l == 0)
      __hip_atomic_fetch_add(bar + w * 32, 1u, __ATOMIC_RELAXED, __HIP_MEMORY_SCOPE_AGENT);

    // zero rotation t+2 (visibility covered by our t+1 arrival's drain)
    {
      u64* z = (u64*)accbuf + (size_t)((t + 2) & 3) * 8192 + c * 256 + tid;
      __hip_atomic_store(z, 0ull, __ATOMIC_RELAXED, __HIP_MEMORY_SCOPE_AGENT);
    }

    // ===== fused poll: all threads poll the 4 wave-arrival counters =====
    {
      const unsigned target = (unsigned)(NCU * (t + 1));
      while (true) {
        unsigned b0 = __hip_atomic_load(bar + 0,  __ATOMIC_RELAXED, __HIP_MEMORY_SCOPE_AGENT);
        unsigned b1 = __hip_atomic_load(bar + 32, __ATOMIC_RELAXED, __HIP_MEMORY_SCOPE_AGENT);
        unsigned b2_ = __hip_atomic_load(bar + 64, __ATOMIC_RELAXED, __HIP_MEMORY_SCOPE_AGENT);
        unsigned b3 = __hip_atomic_load(bar + 96, __ATOMIC_RELAXED, __HIP_MEMORY_SCOPE_AGENT);
        if (umin2(umin2(b0, b1), umin2(b2_, b3)) >= target) break;
      }
      __builtin_amdgcn_sched_barrier(0);
    }

    // ===== gate: read 4 shards, reduce, update mem (replicated), write out =====
    {
      const u64* av = (const u64*)accbuf + (size_t)(t & 3) * 8192;
      const int base = mg * 256 + (tid & 31) * 8;
      u64 vals[4][8];
#pragma unroll
      for (int s = 0; s < 4; s++)
#pragma unroll
        for (int q8 = 0; q8 < 8; q8++)
          vals[s][q8] = __hip_atomic_load(av + s * 2048 + base + q8,
                                          __ATOMIC_RELAXED, __HIP_MEMORY_SCOPE_AGENT);
      // prefetch pre1 for t+1 (issued after gate loads; completes under next compute)
      if (ep && t + 1 < TSTEPS) {
        const float* pb = p1base + (size_t)(t + 1) * 8192;
#pragma unroll
        for (int rr = 0; rr < 4; rr++) p1r[rr] = pb[rr * 32];
      }
      float nmv[16];
#pragma unroll
      for (int q8 = 0; q8 < 8; q8++) {
#pragma unroll
        for (int hlf = 0; hlf < 2; hlf++) {
          const int q = 2 * q8 + hlf;
          float v = 0.f;
#pragma unroll
          for (int s = 0; s < 4; s++) {
            u64 x8 = vals[s][q8];
            v += __uint_as_float((unsigned)(hlf ? (x8 >> 32) : x8));
          }
          float prop = v + b2r[q];
          float g = 1.0f / (1.0f + __expf(-prop));
          float nm = memr[q] + g * (prop - memr[q]);
          memr[q] = nm;
          nmv[q] = nm;
        }
      }
      s16x8 vh0, vl0, vh1, vl1;
#pragma unroll
      for (int q = 0; q < 8; q++) {
        short hi = f2bf(nmv[q]);
        vh0[q] = hi; vl0[q] = f2bf(nmv[q] - bf2f(hi));
        short hi2 = f2bf(nmv[q + 8]);
        vh1[q] = hi2; vl1[q] = f2bf(nmv[q + 8] - bf2f(hi2));
      }
      *(s16x8*)(memh + mg * 520 + i0own) = vh0;
      *(s16x8*)(memh + mg * 520 + i0own + 8) = vh1;
      *(s16x8*)(meml + mg * 520 + i0own) = vl0;
      *(s16x8*)(meml + mg * 520 + i0own + 8) = vl1;
      if ((tid & 31) == c) {
        float* op = out + ((size_t)mg * TSTEPS + t) * 512 + i0own;
#pragma unroll
        for (int q4 = 0; q4 < 4; q4++) {
          f32x4 v;
#pragma unroll
          for (int j = 0; j < 4; j++) v[j] = nmv[q4 * 4 + j];
          *(f32x4*)(op + q4 * 4) = v;
        }
      }
    }
    __syncthreads();                                     // sync3: mem ready
  }
}

extern "C" void kernel_launch(void* const* d_in, const int* in_sizes, int n_in,
                              void* d_out, int out_size, void* d_ws, size_t ws_size,
                              hipStream_t stream) {
  const float* x  = (const float*)d_in[0];
  const float* W1 = (const float*)d_in[1];
  const float* b1 = (const float*)d_in[2];
  const float* W2 = (const float*)d_in[3];
  const float* b2 = (const float*)d_in[4];
  float* out = (float*)d_out;
  char* ws = (char*)d_ws;

  // workspace layout
  float*    accbuf = (float*)(ws + 0);            // 4 rot x 4 shard x 4096 f32 = 262,144 B
  unsigned* bar    = (unsigned*)(ws + 262144);    // 4 counters, 128 B apart
  float*    pre1   = (float*)(ws + (1u << 21));   // [t][cu][m][32] = 134,217,728 B

  hipMemsetAsync(ws, 0, 262144 + 512, stream);

  dim3 gp(256, 8);
  pre_gemm<<<gp, dim3(256), 0, stream>>>(x, W1, b1, pre1);

  const int LDS_BYTES = 162496;
  hipFuncSetAttribute((const void*)seq_scan,
                      hipFuncAttributeMaxDynamicSharedMemorySize, LDS_BYTES);
  seq_scan<<<dim3(NCU), dim3(256), LDS_BYTES, stream>>>(
      W1, W2, b2, pre1, out, accbuf, bar);
}

// Round 4
// 19278.473 us; speedup vs baseline: 2.2097x; 2.2097x over previous
//
#include <hip/hip_runtime.h>
#include <cmath>

typedef __attribute__((ext_vector_type(4))) float f32x4;
typedef __attribute__((ext_vector_type(8))) short s16x8;
typedef __attribute__((ext_vector_type(4))) short s16x4;
typedef unsigned long long u64;

#define TSTEPS 4096
#define NCU 32

__device__ __forceinline__ short f2bf(float f) {
  unsigned u = __float_as_uint(f);
  unsigned r = (u + 0x7FFFu + ((u >> 16) & 1u)) >> 16;
  return (short)r;
}
__device__ __forceinline__ float bf2f(short s) {
  return __uint_as_float(((unsigned)(unsigned short)s) << 16);
}

// LDS-only barrier: wait DS ops, skip vmcnt drain (rule #18: sched_barrier fences)
__device__ __forceinline__ void bar_lds() {
  __builtin_amdgcn_sched_barrier(0);
  asm volatile("s_waitcnt lgkmcnt(0)" ::: "memory");
  __builtin_amdgcn_s_barrier();
  __builtin_amdgcn_sched_barrier(0);
}

// ---- pre1 layout: [t][cu][m][32j] : idx = t*8192 + cu*256 + m*32 + jl ----
__global__ void __launch_bounds__(256) pre_gemm(
    const float* __restrict__ x, const float* __restrict__ W1,
    const float* __restrict__ b1, float* __restrict__ pre1)
{
  __shared__ float As[16][136];
  __shared__ float Bs[16][136];
  const int tid = threadIdx.x;
  const int m0 = blockIdx.x * 128, j0 = blockIdx.y * 128;
  const int r = tid >> 1, half = tid & 1;
  const int tx = tid & 15, ty = tid >> 4;

  float acc[8][8];
#pragma unroll
  for (int a = 0; a < 8; a++)
#pragma unroll
    for (int b = 0; b < 8; b++) acc[a][b] = 0.f;

  const int row = m0 + r;  // row = t*8 + b
  const float* xrow = x + (((size_t)(row & 7) * 4096) + (size_t)(row >> 3)) * 512;
  const float* wrow = W1 + (size_t)(j0 + r) * 1024;  // W1a = cols [0,512)

  for (int k0 = 0; k0 < 512; k0 += 16) {
    f32x4 a0 = *(const f32x4*)(xrow + k0 + half * 8);
    f32x4 a1 = *(const f32x4*)(xrow + k0 + half * 8 + 4);
    f32x4 w0 = *(const f32x4*)(wrow + k0 + half * 8);
    f32x4 w1 = *(const f32x4*)(wrow + k0 + half * 8 + 4);
    __syncthreads();
#pragma unroll
    for (int q = 0; q < 4; q++) {
      As[half * 8 + q][r] = a0[q];
      As[half * 8 + 4 + q][r] = a1[q];
      Bs[half * 8 + q][r] = w0[q];
      Bs[half * 8 + 4 + q][r] = w1[q];
    }
    __syncthreads();
#pragma unroll
    for (int kk = 0; kk < 16; kk++) {
      f32x4 ra0 = *(const f32x4*)&As[kk][ty * 8];
      f32x4 ra1 = *(const f32x4*)&As[kk][ty * 8 + 4];
      f32x4 rb0 = *(const f32x4*)&Bs[kk][tx * 8];
      f32x4 rb1 = *(const f32x4*)&Bs[kk][tx * 8 + 4];
#pragma unroll
      for (int a = 0; a < 4; a++)
#pragma unroll
        for (int b = 0; b < 4; b++) {
          acc[a][b]         += ra0[a] * rb0[b];
          acc[a][b + 4]     += ra0[a] * rb1[b];
          acc[a + 4][b]     += ra1[a] * rb0[b];
          acc[a + 4][b + 4] += ra1[a] * rb1[b];
        }
    }
  }
  float bias[8];
#pragma unroll
  for (int b = 0; b < 8; b++) bias[b] = b1[j0 + tx * 8 + b];

  const int tt = (m0 >> 3) + ty;
  const int col0 = j0 + tx * 8;
  const int c2 = col0 >> 5, jl0 = col0 & 31;
  float* dst = pre1 + (size_t)tt * 8192 + (size_t)c2 * 256 + jl0;
#pragma unroll
  for (int a = 0; a < 8; a++) {
    f32x4 v0, v1;
#pragma unroll
    for (int b = 0; b < 4; b++) { v0[b] = acc[a][b] + bias[b]; v1[b] = acc[a][b + 4] + bias[b + 4]; }
    *(f32x4*)(dst + a * 32) = v0;
    *(f32x4*)(dst + a * 32 + 4) = v1;
  }
}

// ---------------- persistent sequential scan: 32 blocks, j-sliced ----------------
__global__ void __launch_bounds__(256) seq_scan(
    const float* __restrict__ W1, const float* __restrict__ W2,
    const float* __restrict__ b2, const float* __restrict__ pre1,
    float* __restrict__ out, float* __restrict__ accbuf,
    unsigned* __restrict__ bar)
{
  const int c = blockIdx.x;          // 0..31, owns j in [32c, 32c+32)
  const int tid = threadIdx.x;
  const int l = tid & 63;
  const int w = tid >> 6;            // wave 0..3

  extern __shared__ char lds[];
  short* w1bh = (short*)lds;                 // [32][520]
  short* w1bl = w1bh + 32 * 520;
  short* w2h  = w1bl + 32 * 520;             // [512][36]
  short* w2l  = w2h + 512 * 36;
  short* memh = w2l + 512 * 36;              // [9][520]
  short* meml = memh + 9 * 520;
  short* hh   = meml + 9 * 520;              // [9][40]
  short* hl   = hh + 9 * 40;
  float* scr  = (float*)(hl + 9 * 40);       // 512 f32

  // ---- preload weight slices into LDS as bf16 hi/lo splits ----
  for (int e = tid; e < 32 * 128; e += 256) {
    int jl = e >> 7, k4 = (e & 127) << 2;
    f32x4 v = *(const f32x4*)(W1 + (size_t)(c * 32 + jl) * 1024 + 512 + k4);
#pragma unroll
    for (int q = 0; q < 4; q++) {
      short hi = f2bf(v[q]);
      w1bh[jl * 520 + k4 + q] = hi;
      w1bl[jl * 520 + k4 + q] = f2bf(v[q] - bf2f(hi));
    }
  }
  for (int e = tid; e < 512 * 8; e += 256) {
    int i = e >> 3, j4 = (e & 7) << 2;
    f32x4 v = *(const f32x4*)(W2 + (size_t)i * 1024 + c * 32 + j4);
#pragma unroll
    for (int q = 0; q < 4; q++) {
      short hi = f2bf(v[q]);
      w2h[i * 36 + j4 + q] = hi;
      w2l[i * 36 + j4 + q] = f2bf(v[q] - bf2f(hi));
    }
  }
  for (int e = tid; e < 9 * 520; e += 256) { memh[e] = 0; meml[e] = 0; }
  for (int e = tid; e < 9 * 40; e += 256)  { hh[e] = 0; hl[e] = 0; }

  // gate-phase ownership: (m = tid>>5, i = (tid&31)*16 + q)
  const int mg = tid >> 5;
  const int i0own = (tid & 31) * 16;
  float memr[16];
  float b2r[16];
#pragma unroll
  for (int q = 0; q < 16; q++) { memr[q] = 0.f; b2r[q] = b2[i0own + q]; }

  // phase-1 epilogue threads: waves 0,1 lanes 0..31 own (m = (l>>4)*4+rr, jg)
  const int jt = w & 1, kh = w >> 1;
  const int m_ep = (l >> 4) * 4;
  const bool ep = (w < 2) && (l < 32);
  const float* p1base = pre1 + (size_t)c * 256 + m_ep * 32 + jt * 16 + (l & 15);
  float p1r[4];
  if (ep) {
#pragma unroll
    for (int rr = 0; rr < 4; rr++) p1r[rr] = p1base[rr * 32];   // t=0
  }

  const int arow = ((l & 15) < 8) ? (l & 15) : 8;
  const int aoff = arow * 520 + (l >> 4) * 8;
  const int boff = (jt * 16 + (l & 15)) * 520 + (l >> 4) * 8;
  const int haoff = arow * 40 + (l >> 4) * 8;

  __syncthreads();

  for (int t = 0; t < TSTEPS; t++) {
    // ===== phase 1: h[:, our 32 j] = gelu(pre1 + mem @ W1b^T) =====
    {
      f32x4 a0 = {0.f,0.f,0.f,0.f}, a1 = a0, a2 = a0;
#pragma unroll
      for (int ks = 0; ks < 8; ks++) {
        const int ko = kh * 256 + ks * 32;
        s16x8 ah = *(const s16x8*)(memh + aoff + ko);
        s16x8 al = *(const s16x8*)(meml + aoff + ko);
        s16x8 bh = *(const s16x8*)(w1bh + boff + ko);
        s16x8 bl = *(const s16x8*)(w1bl + boff + ko);
        a0 = __builtin_amdgcn_mfma_f32_16x16x32_bf16(ah, bh, a0, 0, 0, 0);
        a1 = __builtin_amdgcn_mfma_f32_16x16x32_bf16(al, bh, a1, 0, 0, 0);
        a2 = __builtin_amdgcn_mfma_f32_16x16x32_bf16(ah, bl, a2, 0, 0, 0);
      }
      f32x4 acc = a0 + a1 + a2;
      if (w >= 2) *(f32x4*)(scr + (w - 2) * 256 + l * 4) = acc;
      bar_lds();                                         // sync1: scr ready (LDS only)
      if (w < 2) {
        acc += *(const f32x4*)(scr + w * 256 + l * 4);
        if (l < 32) {
#pragma unroll
          for (int rr = 0; rr < 4; rr++) {
            float xv = acc[rr] + p1r[rr];
            float hv = 0.5f * xv * (1.0f + erff(xv * 0.70710678118654752f));
            short hhi = f2bf(hv);
            hh[(m_ep + rr) * 40 + jt * 16 + (l & 15)] = hhi;
            hl[(m_ep + rr) * 40 + jt * 16 + (l & 15)] = f2bf(hv - bf2f(hhi));
          }
        }
      }
    }
    bar_lds();                                           // sync2: h ready (LDS only)

    // ===== phase 2: partial[m,i] += h_slice @ W2_slice^T, atomicAdd into IC =====
    {
      float* accw = accbuf + (size_t)(t & 3) * 4096;
      s16x8 ha = *(const s16x8*)(hh + haoff);
      s16x8 hb = *(const s16x8*)(hl + haoff);
      const int n0 = w * 128;
#pragma unroll
      for (int tt = 0; tt < 8; tt++) {
        const int tl = (tt + c) & 7;                 // rotate tile order per CU
        const int icol = n0 + tl * 16 + (l & 15);
        const int woff = icol * 36 + (l >> 4) * 8;
        s16x8 bh, bl;
        *(s16x4*)&bh = *(const s16x4*)(w2h + woff);
        *((s16x4*)&bh + 1) = *(const s16x4*)(w2h + woff + 4);
        *(s16x4*)&bl = *(const s16x4*)(w2l + woff);
        *((s16x4*)&bl + 1) = *(const s16x4*)(w2l + woff + 4);
        f32x4 p0 = {0.f,0.f,0.f,0.f}, p1 = p0, p2 = p0;
        p0 = __builtin_amdgcn_mfma_f32_16x16x32_bf16(ha, bh, p0, 0, 0, 0);
        p1 = __builtin_amdgcn_mfma_f32_16x16x32_bf16(hb, bh, p1, 0, 0, 0);
        p2 = __builtin_amdgcn_mfma_f32_16x16x32_bf16(ha, bl, p2, 0, 0, 0);
        f32x4 p = p0 + p1 + p2;
        if (l < 32) {
          const int mrow = (l >> 4) * 4;
#pragma unroll
          for (int rr = 0; rr < 4; rr++)
            atomicAdd(accw + ((mrow + rr) << 9) + icol, p[rr]);
        }
      }
    }

    // ===== arrival: full drain (atomics) then single no-return add =====
    __syncthreads();                                     // drains vmcnt(0): atomics visible
    if (tid == 0)
      __hip_atomic_fetch_add(bar, 1u, __ATOMIC_RELAXED, __HIP_MEMORY_SCOPE_AGENT);

    // zero rotation t+2 (drained by next full sync; read of t+2 rotation long done)
    if (tid < 64) {
      u64* z = (u64*)accbuf + (size_t)((t + 2) & 3) * 2048 + c * 64 + tid;
      __hip_atomic_store(z, 0ull, __ATOMIC_RELAXED, __HIP_MEMORY_SCOPE_AGENT);
    }

    // prefetch pre1 for t+1: hides under the poll / others' pre-sync drain
    if (ep && t + 1 < TSTEPS) {
      const float* pb = p1base + (size_t)(t + 1) * 8192;
#pragma unroll
      for (int rr = 0; rr < 4; rr++) p1r[rr] = pb[rr * 32];
    }

    // ===== poll: tid0 only (32 pollers device-wide), then broadcast =====
    if (tid == 0) {
      const unsigned target = (unsigned)(NCU * (t + 1));
      while (__hip_atomic_load(bar, __ATOMIC_RELAXED, __HIP_MEMORY_SCOPE_AGENT) < target) {}
    }
    __syncthreads();

    // ===== gate: read reduced proposed, update mem (replicated), write out =====
    {
      const u64* av = (const u64*)accbuf + (size_t)(t & 3) * 2048;
      u64 vals[8];
#pragma unroll
      for (int q8 = 0; q8 < 8; q8++)
        vals[q8] = __hip_atomic_load(av + tid * 8 + q8, __ATOMIC_RELAXED, __HIP_MEMORY_SCOPE_AGENT);
      float nmv[16];
#pragma unroll
      for (int q8 = 0; q8 < 8; q8++) {
#pragma unroll
        for (int hlf = 0; hlf < 2; hlf++) {
          const int q = 2 * q8 + hlf;
          float v = __uint_as_float((unsigned)(hlf ? (vals[q8] >> 32) : vals[q8]));
          float prop = v + b2r[q];
          float g = 1.0f / (1.0f + __expf(-prop));
          float nm = memr[q] + g * (prop - memr[q]);
          memr[q] = nm;
          nmv[q] = nm;
        }
      }
      s16x8 vh0, vl0, vh1, vl1;
#pragma unroll
      for (int q = 0; q < 8; q++) {
        short hi = f2bf(nmv[q]);
        vh0[q] = hi; vl0[q] = f2bf(nmv[q] - bf2f(hi));
        short hi2 = f2bf(nmv[q + 8]);
        vh1[q] = hi2; vl1[q] = f2bf(nmv[q + 8] - bf2f(hi2));
      }
      *(s16x8*)(memh + mg * 520 + i0own) = vh0;
      *(s16x8*)(memh + mg * 520 + i0own + 8) = vh1;
      *(s16x8*)(meml + mg * 520 + i0own) = vl0;
      *(s16x8*)(meml + mg * 520 + i0own + 8) = vl1;
      if ((tid & 31) == c) {
        float* op = out + ((size_t)mg * TSTEPS + t) * 512 + i0own;
#pragma unroll
        for (int q4 = 0; q4 < 4; q4++) {
          f32x4 v;
#pragma unroll
          for (int j = 0; j < 4; j++) v[j] = nmv[q4 * 4 + j];
          *(f32x4*)(op + q4 * 4) = v;
        }
      }
    }
    bar_lds();   // sync3: mem LDS ready; out-store drains later at next full sync
  }
}

extern "C" void kernel_launch(void* const* d_in, const int* in_sizes, int n_in,
                              void* d_out, int out_size, void* d_ws, size_t ws_size,
                              hipStream_t stream) {
  const float* x  = (const float*)d_in[0];
  const float* W1 = (const float*)d_in[1];
  const float* b1 = (const float*)d_in[2];
  const float* W2 = (const float*)d_in[3];
  const float* b2 = (const float*)d_in[4];
  float* out = (float*)d_out;
  char* ws = (char*)d_ws;

  // workspace layout
  float*    accbuf = (float*)(ws + 0);            // 4 rot x 4096 f32 = 65,536 B
  unsigned* bar    = (unsigned*)(ws + 65536);     // 1 counter
  float*    pre1   = (float*)(ws + (1u << 20));   // [t][cu][m][32] = 134,217,728 B

  hipMemsetAsync(ws, 0, 65536 + 256, stream);

  dim3 gp(256, 8);
  pre_gemm<<<gp, dim3(256), 0, stream>>>(x, W1, b1, pre1);

  const int LDS_BYTES = 162496;
  hipFuncSetAttribute((const void*)seq_scan,
                      hipFuncAttributeMaxDynamicSharedMemorySize, LDS_BYTES);
  seq_scan<<<dim3(NCU), dim3(256), LDS_BYTES, stream>>>(
      W1, W2, b2, pre1, out, accbuf, bar);
}